// Round 8
// baseline (152.378 us; speedup 1.0000x reference)
//
#include <hip/hip_runtime.h>
#include <math.h>

// Problem constants (match reference setup_inputs)
constexpr int Bn = 131072;   // batch
constexpr int Fn = 1024;     // features (= GEMM K)
constexpr int Tn = 100;      // trees
constexpr int Kn = 32;       // features per tree

constexpr int TP  = 112;           // trees padded to 7*16 (GEMM N)
constexpr int NF  = TP / 16;       // 7 B-fragments
constexpr int BK  = 64;            // floats per row per tile
constexpr int NT  = Fn / BK;       // 16 tiles
constexpr int BM  = 128;           // rows per block
constexpr int MW  = 32;            // rows per wave (wave-private)
constexpr int WPB = 4;
constexpr int BLOCK = 256;
constexpr int GRID  = Bn / BM;     // 1024 blocks

typedef __attribute__((ext_vector_type(8))) short bf16x8;
typedef __attribute__((ext_vector_type(4))) float f32x4;

// fp32 -> bf16 round-to-nearest-even
__device__ inline unsigned short f2bf(float f) {
    uint32_t u = __float_as_uint(f);
    return (unsigned short)((u + 0x7FFFu + ((u >> 16) & 1u)) >> 16);
}

__device__ inline bf16x8 cvt8(f32x4 lo, f32x4 hi) {
    bf16x8 v;
    v[0] = (short)f2bf(lo[0]); v[1] = (short)f2bf(lo[1]);
    v[2] = (short)f2bf(lo[2]); v[3] = (short)f2bf(lo[3]);
    v[4] = (short)f2bf(hi[0]); v[5] = (short)f2bf(hi[1]);
    v[6] = (short)f2bf(hi[2]); v[7] = (short)f2bf(hi[3]);
    return v;
}

// ---------------------------------------------------------------------------
// Prep: dense W_T bf16 [TP][Fn] + bias[TP] in workspace (unchanged, validated)
// ---------------------------------------------------------------------------
__global__ __launch_bounds__(64)
void rf_prep(const int* __restrict__ fidx, const float* __restrict__ fthr,
             const float* __restrict__ fw,
             unsigned short* __restrict__ wt, float* __restrict__ bias)
{
    const int t    = blockIdx.x;     // 0..111
    const int lane = threadIdx.x;    // 0..63

    int4 z = make_int4(0, 0, 0, 0);
    int4* rowp = (int4*)(wt + (size_t)t * Fn);
    rowp[lane * 2 + 0] = z;
    rowp[lane * 2 + 1] = z;
    __syncthreads();

    float bsum = 0.f;
    if (t < Tn && lane < Kn) {
        const int   idx = fidx[t * Kn + lane];
        const float w   = fw[t * Kn + lane];
        const float th  = fthr[t * Kn + lane];
        wt[(size_t)t * Fn + idx] = f2bf(w);
        bsum = th * w;
    }
#pragma unroll
    for (int d = 1; d < 64; d <<= 1) bsum += __shfl_xor(bsum, d, 64);
    if (lane == 0) bias[t] = (t < Tn) ? bsum : 0.f;
}

// ---------------------------------------------------------------------------
// Reg-staged barrier-free GEMM, R7 load path: nontemporal per-lane dwordx4
// -> 8 NAMED f32x4 -> ds_write_b128 (XOR-swizzled) -> ds_read_b128 -> cvt ->
// MFMA.  No global_load_lds, no arrays in hot path (R5 scratch lesson).
// Wave-private LDS double buffer (2 x 8 KB/wave), no __syncthreads.
// Correctness of all waits is compiler reg-dep-guaranteed; manual vmcnts
// only pace the pipeline (A one tile ahead, B per tile).
// ---------------------------------------------------------------------------

// Stage-load tile T: instr i covers rows i*4+(lane>>4), 256 B contiguous per
// 16-lane group.  paA = x + (rb+wid*32+sub)*Fn + c*4 ; instr stride 16 KB.
#define NTLD8(T, A0,A1,A2,A3,A4,A5,A6,A7) do {                             \
    const char* _p = (const char*)paA + (size_t)(T) * 256;                 \
    A0 = __builtin_nontemporal_load((const f32x4*)(_p + 0 * 16384));       \
    A1 = __builtin_nontemporal_load((const f32x4*)(_p + 1 * 16384));       \
    A2 = __builtin_nontemporal_load((const f32x4*)(_p + 2 * 16384));       \
    A3 = __builtin_nontemporal_load((const f32x4*)(_p + 3 * 16384));       \
    A4 = __builtin_nontemporal_load((const f32x4*)(_p + 4 * 16384));       \
    A5 = __builtin_nontemporal_load((const f32x4*)(_p + 5 * 16384));       \
    A6 = __builtin_nontemporal_load((const f32x4*)(_p + 6 * 16384));       \
    A7 = __builtin_nontemporal_load((const f32x4*)(_p + 7 * 16384));       \
} while (0)

// ds_write the 8 staged regs into buffer at byte offset BUFB (0 or 8192).
#define DSWR8(BUFB, A0,A1,A2,A3,A4,A5,A6,A7) do {                          \
    *(f32x4*)(lbase + (BUFB) + w0) = A0;                                   \
    *(f32x4*)(lbase + (BUFB) + w1) = A1;                                   \
    *(f32x4*)(lbase + (BUFB) + w2) = A2;                                   \
    *(f32x4*)(lbase + (BUFB) + w3) = A3;                                   \
    *(f32x4*)(lbase + (BUFB) + w4) = A4;                                   \
    *(f32x4*)(lbase + (BUFB) + w5) = A5;                                   \
    *(f32x4*)(lbase + (BUFB) + w6) = A6;                                   \
    *(f32x4*)(lbase + (BUFB) + w7) = A7;                                   \
} while (0)

// B fragments for tile T: 14 named bf16x8 from L2-resident wt.
// pbB = wt + r*Fn + g*8 ; f stride 32768 B, ks stride 64 B, tile stride 128 B.
#define LOADB(T) do {                                                      \
    const char* _q = (const char*)pbB + (size_t)(T) * 128;                 \
    B00 = *(const bf16x8*)(_q + 0 * 32768);                                \
    B01 = *(const bf16x8*)(_q + 1 * 32768);                                \
    B02 = *(const bf16x8*)(_q + 2 * 32768);                                \
    B03 = *(const bf16x8*)(_q + 3 * 32768);                                \
    B04 = *(const bf16x8*)(_q + 4 * 32768);                                \
    B05 = *(const bf16x8*)(_q + 5 * 32768);                                \
    B06 = *(const bf16x8*)(_q + 6 * 32768);                                \
    B10 = *(const bf16x8*)(_q + 0 * 32768 + 64);                           \
    B11 = *(const bf16x8*)(_q + 1 * 32768 + 64);                           \
    B12 = *(const bf16x8*)(_q + 2 * 32768 + 64);                           \
    B13 = *(const bf16x8*)(_q + 3 * 32768 + 64);                           \
    B14 = *(const bf16x8*)(_q + 4 * 32768 + 64);                           \
    B15 = *(const bf16x8*)(_q + 5 * 32768 + 64);                           \
    B16 = *(const bf16x8*)(_q + 6 * 32768 + 64);                           \
} while (0)

// ds_read one A fragment pair (m, ks) from buffer BUFB (swizzled chunks).
#define READF(M, KS, LO, HI, BUFB) do {                                    \
    const char* _b = lbase + (BUFB) + ((M) * 16 + r) * 256;                \
    LO = *(const f32x4*)(_b + ((((KS) * 8 + g2 + 0) ^ r) * 16));           \
    HI = *(const f32x4*)(_b + ((((KS) * 8 + g2 + 1) ^ r) * 16));           \
} while (0)

#define MFMAROW(AF, Ba,Bb,Bc,Bd,Be,Bf,Bg, a0,a1,a2,a3,a4,a5,a6) do {       \
    a0 = __builtin_amdgcn_mfma_f32_16x16x32_bf16(AF, Ba, a0, 0, 0, 0);     \
    a1 = __builtin_amdgcn_mfma_f32_16x16x32_bf16(AF, Bb, a1, 0, 0, 0);     \
    a2 = __builtin_amdgcn_mfma_f32_16x16x32_bf16(AF, Bc, a2, 0, 0, 0);     \
    a3 = __builtin_amdgcn_mfma_f32_16x16x32_bf16(AF, Bd, a3, 0, 0, 0);     \
    a4 = __builtin_amdgcn_mfma_f32_16x16x32_bf16(AF, Be, a4, 0, 0, 0);     \
    a5 = __builtin_amdgcn_mfma_f32_16x16x32_bf16(AF, Bf, a5, 0, 0, 0);     \
    a6 = __builtin_amdgcn_mfma_f32_16x16x32_bf16(AF, Bg, a6, 0, 0, 0);     \
} while (0)

// One pipeline phase consuming tile TC from buffer CB, staging into OB.
#define PHASE(TC, CB, OB) do {                                             \
    LOADB(TC);                                                             \
    READF(0, 0, L0, L1, CB);                                               \
    READF(1, 0, L2, L3, CB);                                               \
    READF(0, 1, L4, L5, CB);                                               \
    READF(1, 1, L6, L7, CB);                                               \
    asm volatile("s_waitcnt vmcnt(14)" ::: "memory");  /* A(TC+1) landed */ \
    DSWR8(OB, A0, A1, A2, A3, A4, A5, A6, A7);                             \
    if ((TC) + 2 < NT) NTLD8((TC) + 2, A0, A1, A2, A3, A4, A5, A6, A7);    \
    {                                                                      \
        bf16x8 _af;                                                        \
        _af = cvt8(L0, L1);                                                \
        MFMAROW(_af, B00, B01, B02, B03, B04, B05, B06,                    \
                acc00, acc01, acc02, acc03, acc04, acc05, acc06);          \
        _af = cvt8(L2, L3);                                                \
        MFMAROW(_af, B00, B01, B02, B03, B04, B05, B06,                    \
                acc10, acc11, acc12, acc13, acc14, acc15, acc16);          \
        _af = cvt8(L4, L5);                                                \
        MFMAROW(_af, B10, B11, B12, B13, B14, B15, B16,                    \
                acc00, acc01, acc02, acc03, acc04, acc05, acc06);          \
        _af = cvt8(L6, L7);                                                \
        MFMAROW(_af, B10, B11, B12, B13, B14, B15, B16,                    \
                acc10, acc11, acc12, acc13, acc14, acc15, acc16);          \
    }                                                                      \
} while (0)

__global__ __launch_bounds__(BLOCK)
void rf_gemm(const float* __restrict__ x,
             const unsigned short* __restrict__ wt,
             const float* __restrict__ bias,
             float* __restrict__ out)
{
    __shared__ float lds[WPB][2][MW * BK];   // 4 waves x 2 x 8 KB = 64 KB

    const int lane = threadIdx.x & 63;
    const int wid  = threadIdx.x >> 6;
    const int rb   = blockIdx.x * BM;
    const int r    = lane & 15;
    const int g    = lane >> 4;
    const int g2   = g * 2;
    const int sub  = lane >> 4;     // staging row-within-quad
    const int c    = lane & 15;     // staging logical 16B chunk

    // staging global base: row rb + wid*32 + sub, byte col c*16
    const char* paA = (const char*)(x + (size_t)(rb + wid * MW + sub) * Fn) + c * 16;
    // B global base: row r of fragment 0, k-offset g*8 shorts
    const char* pbB = (const char*)(wt + (size_t)r * Fn + g * 8);
    // LDS wave base
    char* lbase = (char*)&lds[wid][0][0];

    // ds_write byte offsets: instr i -> row i*4+sub, phys chunk c ^ (row&15)
    const int w0 = (0 * 4 + sub) * 256 + ((c ^ ((0 * 4 + sub) & 15)) * 16);
    const int w1 = (1 * 4 + sub) * 256 + ((c ^ ((1 * 4 + sub) & 15)) * 16);
    const int w2 = (2 * 4 + sub) * 256 + ((c ^ ((2 * 4 + sub) & 15)) * 16);
    const int w3 = (3 * 4 + sub) * 256 + ((c ^ ((3 * 4 + sub) & 15)) * 16);
    const int w4 = (4 * 4 + sub) * 256 + ((c ^ ((4 * 4 + sub) & 15)) * 16);
    const int w5 = (5 * 4 + sub) * 256 + ((c ^ ((5 * 4 + sub) & 15)) * 16);
    const int w6 = (6 * 4 + sub) * 256 + ((c ^ ((6 * 4 + sub) & 15)) * 16);
    const int w7 = (7 * 4 + sub) * 256 + ((c ^ ((7 * 4 + sub) & 15)) * 16);

    f32x4 acc00 = {0,0,0,0}, acc01 = {0,0,0,0}, acc02 = {0,0,0,0},
          acc03 = {0,0,0,0}, acc04 = {0,0,0,0}, acc05 = {0,0,0,0},
          acc06 = {0,0,0,0};
    f32x4 acc10 = {0,0,0,0}, acc11 = {0,0,0,0}, acc12 = {0,0,0,0},
          acc13 = {0,0,0,0}, acc14 = {0,0,0,0}, acc15 = {0,0,0,0},
          acc16 = {0,0,0,0};

    f32x4 A0, A1, A2, A3, A4, A5, A6, A7;
    f32x4 L0, L1, L2, L3, L4, L5, L6, L7;
    bf16x8 B00, B01, B02, B03, B04, B05, B06;
    bf16x8 B10, B11, B12, B13, B14, B15, B16;

    // Prologue: A(0) -> buf0 (reg-dep wait), A(1) left in flight.
    NTLD8(0, A0, A1, A2, A3, A4, A5, A6, A7);
    DSWR8(0, A0, A1, A2, A3, A4, A5, A6, A7);
    NTLD8(1, A0, A1, A2, A3, A4, A5, A6, A7);

    for (int t = 0; t < NT; t += 2) {
        PHASE(t, 0, 8192);          // consume tile t (buf0), stage t+1 -> buf1
        PHASE(t + 1, 8192, 0);      // consume tile t+1 (buf1), stage t+2 -> buf0
    }

    // ---- epilogue: ws = acc - bias; p = sigmoid; mean over trees ----
    f32x4 accA[2][NF] = {
        { acc00, acc01, acc02, acc03, acc04, acc05, acc06 },
        { acc10, acc11, acc12, acc13, acc14, acc15, acc16 }
    };

    const int col = lane & 15;     // C col = lane&15, row = (lane>>4)*4 + reg
    float psum[2][4] = {};
#pragma unroll
    for (int f = 0; f < NF; ++f) {
        const int  n     = f * 16 + col;
        const bool valid = n < Tn;
        const float bv   = bias[n];   // zero-padded
#pragma unroll
        for (int m = 0; m < 2; ++m)
#pragma unroll
            for (int q = 0; q < 4; ++q) {
                const float ws = accA[m][f][q] - bv;
                const float p  = 1.f / (1.f + __expf(-ws));
                if (valid) psum[m][q] += p;
            }
    }
#pragma unroll
    for (int m = 0; m < 2; ++m)
#pragma unroll
        for (int q = 0; q < 4; ++q)
#pragma unroll
            for (int d = 1; d < 16; d <<= 1)
                psum[m][q] += __shfl_xor(psum[m][q], d, 64);

#pragma unroll
    for (int m = 0; m < 2; ++m) {
        if (col < 4) {   // lane col==q writes row g*4 + q of this fragment
            const int q   = col;
            const int row = rb + wid * MW + m * 16 + g * 4 + q;
            const float pm = psum[m][q] * (1.0f / Tn);
            *(float2*)(out + (size_t)row * 2) = make_float2(1.0f - pm, pm);
        }
    }
}

extern "C" void kernel_launch(void* const* d_in, const int* in_sizes, int n_in,
                              void* d_out, int out_size, void* d_ws, size_t ws_size,
                              hipStream_t stream) {
    const float* x    = (const float*)d_in[0];
    const int*   fidx = (const int*)  d_in[1];
    const float* fthr = (const float*)d_in[2];
    const float* fw   = (const float*)d_in[3];
    float*       out  = (float*)d_out;

    unsigned short* wt   = (unsigned short*)d_ws;                       // 229376 B
    float*          bias = (float*)((char*)d_ws + (size_t)TP * Fn * 2); // +448 B

    rf_prep<<<TP, 64, 0, stream>>>(fidx, fthr, fw, wt, bias);
    rf_gemm<<<GRID, BLOCK, 0, stream>>>(x, wt, bias, out);
}